// Round 13
// baseline (163.947 us; speedup 1.0000x reference)
//
#include <hip/hip_runtime.h>
#include <hip/hip_fp16.h>
#include <math.h>

// CTC forward loss (warp-ctc semantics). T=1024, B=64, V=128, L=256, S=513.
//
// Round 14: hand-scheduled asm step. Evidence R2..R13: ~60 cyc/step stall
// invariant under memory schemes, instruction cuts, and occupancy changes;
// theory: hipcc's post-RA scheduler assumes multi-wave latency hiding and
// emits adjacent dependent VALU pairs (~11/step x ~5.5 cyc = the tax).
// Fix: the 22-op DP step is ONE inline-asm block, hand-ordered
// 9 adds -> 4 fmacs -> 9 muls with all dependency distances >= 5 instrs
// (>= 10 cyc > VALU latency). Compiler cannot reorder inside asm.
// DPP + cvts + prefetch loads remain in HIP between asm blocks.
// Probs kernel: R13's (plain-order emissions, scalar blanks) unchanged.

#define L2E 1.4426950408889634f
#define LN2 0.6931471805599453f

constexpr int T   = 1024;
constexpr int B   = 64;
constexpr int V   = 128;
constexpr int L   = 256;
constexpr int RW  = 256;        // ushorts per P row: 256 label probs = 512 B
constexpr int TP  = T + 32;     // padded time rows per batch

// ---- DPP helpers (gfx9 ctrl codes: 0x111+ row_shr, 0x138 wave_shr:1,
//      0x142 row_bcast15, 0x143 row_bcast31) ----
template <int CTRL>
__device__ __forceinline__ float fdpp0(float x) {        // invalid lanes -> 0
  return __int_as_float(__builtin_amdgcn_update_dpp(
      0, __float_as_int(x), CTRL, 0xf, 0xf, true));
}
template <int CTRL>
__device__ __forceinline__ float fdppk(float x) {        // invalid lanes -> keep
  return __int_as_float(__builtin_amdgcn_update_dpp(
      __float_as_int(x), __float_as_int(x), CTRL, 0xf, 0xf, false));
}

__device__ __forceinline__ float wave_bcast63(float x) {
  return __int_as_float(__builtin_amdgcn_readlane(__float_as_int(x), 63));
}

__device__ __forceinline__ float wave_max(float x) {     // any sign
  x = fmaxf(x, fdppk<0x111>(x));
  x = fmaxf(x, fdppk<0x112>(x));
  x = fmaxf(x, fdppk<0x114>(x));
  x = fmaxf(x, fdppk<0x118>(x));
  x = fmaxf(x, fdppk<0x142>(x));
  x = fmaxf(x, fdppk<0x143>(x));
  return wave_bcast63(x);
}
__device__ __forceinline__ float wave_sum_nn(float x) {  // x >= 0
  x += fdpp0<0x111>(x);
  x += fdpp0<0x112>(x);
  x += fdpp0<0x114>(x);
  x += fdpp0<0x118>(x);
  x += fdpp0<0x142>(x);
  x += fdpp0<0x143>(x);
  return wave_bcast63(x);
}

__device__ __forceinline__ float h2f(uint bits) {
  return __half2float(__ushort_as_half((ushort)bits));
}

// ---- the hand-scheduled 22-op DP step (one asm block, fixed order) ----
// cells a0..a7 = 8l..8l+7 (a8 = cell 512, lane 63). pc = prev lane's a7.
// Order: 9 independent adds; 4 fmacs (dep dist >= 5); 9 muls (dist >= 5).
__device__ __forceinline__ void step22(
    float& a0, float& a1, float& a2, float& a3, float& a4,
    float& a5, float& a6, float& a7, float& a8,
    float pc, float e0, float e1, float e2, float e3, float eb,
    float f0, float f1, float f2, float f3) {
  float s0, s1, s2, s3, s4, s5, s6, s7, s8;
  asm volatile(
      "v_add_f32 %[s8], %[x8], %[x7]\n\t"
      "v_add_f32 %[s7], %[x7], %[x6]\n\t"
      "v_add_f32 %[s6], %[x6], %[x5]\n\t"
      "v_add_f32 %[s5], %[x5], %[x4]\n\t"
      "v_add_f32 %[s4], %[x4], %[x3]\n\t"
      "v_add_f32 %[s3], %[x3], %[x2]\n\t"
      "v_add_f32 %[s2], %[x2], %[x1]\n\t"
      "v_add_f32 %[s1], %[x1], %[x0]\n\t"
      "v_add_f32 %[s0], %[x0], %[pc]\n\t"
      "v_fmac_f32 %[s7], %[f3], %[x5]\n\t"
      "v_fmac_f32 %[s5], %[f2], %[x3]\n\t"
      "v_fmac_f32 %[s3], %[f1], %[x1]\n\t"
      "v_fmac_f32 %[s1], %[f0], %[pc]\n\t"
      "v_mul_f32 %[x8], %[s8], %[eb]\n\t"
      "v_mul_f32 %[x7], %[s7], %[e3]\n\t"
      "v_mul_f32 %[x6], %[s6], %[eb]\n\t"
      "v_mul_f32 %[x5], %[s5], %[e2]\n\t"
      "v_mul_f32 %[x4], %[s4], %[eb]\n\t"
      "v_mul_f32 %[x3], %[s3], %[e1]\n\t"
      "v_mul_f32 %[x2], %[s2], %[eb]\n\t"
      "v_mul_f32 %[x1], %[s1], %[e0]\n\t"
      "v_mul_f32 %[x0], %[s0], %[eb]\n\t"
      : [s0] "=&v"(s0), [s1] "=&v"(s1), [s2] "=&v"(s2), [s3] "=&v"(s3),
        [s4] "=&v"(s4), [s5] "=&v"(s5), [s6] "=&v"(s6), [s7] "=&v"(s7),
        [s8] "=&v"(s8),
        [x0] "+v"(a0), [x1] "+v"(a1), [x2] "+v"(a2), [x3] "+v"(a3),
        [x4] "+v"(a4), [x5] "+v"(a5), [x6] "+v"(a6), [x7] "+v"(a7),
        [x8] "+v"(a8)
      : [pc] "v"(pc), [e0] "v"(e0), [e1] "v"(e1), [e2] "v"(e2),
        [e3] "v"(e3), [eb] "v"(eb), [f0] "v"(f0), [f1] "v"(f1),
        [f2] "v"(f2), [f3] "v"(f3));
}

// ---------------- prologue: emission probabilities ----------------
// One block per (b, 32-row chunk); 4 waves x 8 rows. Labels loaded once per
// wave. Output PLAIN-ORDER: P row ushort j = prob(lab[j]); blank stored as
// ONE fp32 per (b, t) in Pbk. Block x==32 (rows 1024..1055) is zero pad.
__global__ __launch_bounds__(256) void ctc_probs_kernel(
    const float* __restrict__ acts,        // (T, B, V)
    const int* __restrict__ labels,        // (B, L)
    ushort* __restrict__ P,                // (B, TP, RW) fp16 bits, 512B rows
    float* __restrict__ Pbk) {             // (B, TP) scalar blank probs
  const int w    = threadIdx.x >> 6;
  const int lane = threadIdx.x & 63;
  const int b    = blockIdx.y;
  const int tb   = blockIdx.x * 32 + w * 8;   // first of this wave's 8 rows

  if (tb >= T) {                            // pad rows: zeros
    #pragma unroll
    for (int r = 0; r < 8; ++r) {
      uint2 z; z.x = 0u; z.y = 0u;
      *(uint2*)(P + ((size_t)b * TP + tb + r) * RW + 4 * lane) = z;
    }
    if (lane < 8) Pbk[(size_t)b * TP + tb + lane] = 0.f;
    return;
  }

  // labels once per wave; bpermute addresses/shifts precomputed
  const int4 lvv = *(const int4*)(labels + (size_t)b * L + 4 * lane);
  const int ba0 = (lvv.x & ~1) * 2, sh0 = (lvv.x & 1) << 4;
  const int ba1 = (lvv.y & ~1) * 2, sh1 = (lvv.y & 1) << 4;
  const int ba2 = (lvv.z & ~1) * 2, sh2 = (lvv.z & 1) << 4;
  const int ba3 = (lvv.w & ~1) * 2, sh3 = (lvv.w & 1) << 4;

  #pragma unroll
  for (int r = 0; r < 8; ++r) {
    const int t = tb + r;
    const float* row = acts + ((size_t)t * B + b) * V;
    const float2 v2 = *(const float2*)(row + 2 * lane);
    const float e0 = exp2f(fmaf(v2.x, L2E, -32.0f));
    const float e1 = exp2f(fmaf(v2.y, L2E, -32.0f));
    const float sm = wave_sum_nn(e0 + e1);
    const float rc = __builtin_amdgcn_rcpf(sm);
    const auto pk = __builtin_amdgcn_cvt_pkrtz(e0 * rc, e1 * rc);
    uint hp;                                // [p_{2l} | p_{2l+1} << 16]
    __builtin_memcpy(&hp, &pk, 4);
    const uint g0 = (uint)__builtin_amdgcn_ds_bpermute(ba0, (int)hp);
    const uint g1 = (uint)__builtin_amdgcn_ds_bpermute(ba1, (int)hp);
    const uint g2 = (uint)__builtin_amdgcn_ds_bpermute(ba2, (int)hp);
    const uint g3 = (uint)__builtin_amdgcn_ds_bpermute(ba3, (int)hp);
    const uint h0 = (g0 >> sh0) & 0xffffu;
    const uint h1 = (g1 >> sh1) & 0xffffu;
    const uint h2 = (g2 >> sh2) & 0xffffu;
    const uint h3 = (g3 >> sh3);
    uint2 o;
    o.x = h0 | (h1 << 16);                  // PLAIN order: labels 4l,4l+1
    o.y = h2 | (h3 << 16);                  //              labels 4l+2,4l+3
    *(uint2*)(P + ((size_t)b * TP + t) * RW + 4 * lane) = o;
    if (lane == 0)
      Pbk[(size_t)b * TP + t] = e0 * rc;    // vocab 0 = lane0's p0
  }
}

// ---------------- DP kernel: one wave per batch ----------------
// Lane l owns cells 8l..8l+7 as scalars a0..a7; lane 63 owns cell 512 (a8).
__global__ __launch_bounds__(64) void ctc_dp_kernel(
    const ushort* __restrict__ P,
    const float* __restrict__ Pbk,
    const int* __restrict__ labels,
    const int* __restrict__ act_lens,
    const int* __restrict__ label_lens,
    float* __restrict__ out) {
  const int b    = blockIdx.x;
  const int lane = threadIdx.x;
  const ushort* __restrict__ Pb = P + (size_t)b * TP * RW;
  const float*  __restrict__ Bk = Pbk + (size_t)b * TP;

  // skip-transition flags for the 4 odd cells (labels 4l..4l+3)
  const int4 lv   = *(const int4*)(labels + (size_t)b * L + 4 * lane);
  const int prevw = __builtin_amdgcn_update_dpp(0, lv.w, 0x138, 0xf, 0xf, true);
  const float f0 = (lane > 0 && lv.x != 0 && lv.x != prevw) ? 1.f : 0.f;
  const float f1 = (lv.y != 0 && lv.y != lv.x) ? 1.f : 0.f;
  const float f2 = (lv.z != 0 && lv.z != lv.y) ? 1.f : 0.f;
  const float f3 = (lv.w != 0 && lv.w != lv.z) ? 1.f : 0.f;

  const int AL = act_lens[b];

  // ---- t=0 init (linear domain; unreachable cells = 0) ----
  float a0=0.f,a1=0.f,a2=0.f,a3=0.f,a4=0.f,a5=0.f,a6=0.f,a7=0.f,a8=0.f;
  {
    const uint2 u0 = *(const uint2*)(Pb + 4 * lane);
    const float eb0 = Bk[0];
    const float e00 = h2f(u0.x);            // p(lab0, t=0)
    if (lane == 0) { a0 = eb0; a1 = e00; }
  }
  int iacc = 0;        // accumulated log2 of renorm scales (wave-uniform)
  float pend = 1.0f;   // wave-maxed state max, measured 2 steps before apply

  auto measure = [&]() {                    // start wave-max; used 2 steps on
    float m = fmaxf(fmaxf(fmaxf(a0, a1), fmaxf(a2, a3)),
                    fmaxf(fmaxf(a4, a5), fmaxf(a6, a7)));
    m = fmaxf(m, a8);
    pend = wave_max(m);
  };
  auto apply = [&]() {                      // pow-2 scale 2^(175-e), exact.
    // +48 headroom (validated R10/R11/R12, absmax 0 at 16-step cadence)
    const uint mb = __float_as_uint(pend);
    int e = (int)((mb >> 23) & 0xffu); if (e < 48) e = 48;
    const float r = __uint_as_float((uint)(302 - e) << 23);
    iacc += (e - 175);
    a0*=r; a1*=r; a2*=r; a3*=r; a4*=r; a5*=r; a6*=r; a7*=r; a8*=r;
  };

  // ---- rolling prefetch: emissions 16 rows deep + scalar blanks ----
  uint2 evi[16];
  float ebs[16];
  #pragma unroll
  for (int k = 0; k < 16; ++k) {
    evi[k] = *(const uint2*)(Pb + (size_t)(1 + k) * RW + 4 * lane);
    ebs[k] = Bk[1 + k];
  }

  const ushort* pf = Pb + (size_t)17 * RW;  // row t+16 for t=1
  int t0 = 1;
  #pragma unroll 1
  for (int blk = 0; blk < 64; ++blk) {      // 64 x 16 = steps t=1..1024
    const ushort* pfA = pf;                 // dual bases: offsets fit 13-bit
    const ushort* pfB = pf + (size_t)8 * RW;
    const float*  bf  = Bk + (t0 + 16);     // rows <= 1040 < TP, pad zeroed
    const bool fast = (t0 + 16 <= AL);
    if (fast) {
      #pragma unroll
      for (int k = 0; k < 16; ++k) {
        const uint2 uu = evi[k];
        const float ebv = ebs[k];
        evi[k] = *(const uint2*)(((k < 8) ? pfA : pfB)
                                 + (size_t)(k & 7) * RW + 4 * lane);
        ebs[k] = bf[k];
        const float pc = fdpp0<0x138>(a7);  // prev lane's a7 (lane0 -> 0)
        const float e0 = h2f(uu.x);
        const float e1 = h2f(uu.x >> 16);
        const float e2 = h2f(uu.y);
        const float e3 = h2f(uu.y >> 16);
        step22(a0,a1,a2,a3,a4,a5,a6,a7,a8, pc, e0,e1,e2,e3, ebv,
               f0,f1,f2,f3);
        if (k == 13) measure();
        if (k == 15) apply();
      }
    } else {
      #pragma unroll
      for (int k = 0; k < 16; ++k) {
        const uint2 uu = evi[k];
        const float ebv = ebs[k];
        evi[k] = *(const uint2*)(((k < 8) ? pfA : pfB)
                                 + (size_t)(k & 7) * RW + 4 * lane);
        ebs[k] = bf[k];
        if ((t0 + k) < AL) {                // AL wave-uniform: scalar branch
          const float pc = fdpp0<0x138>(a7);
          const float e0 = h2f(uu.x);
          const float e1 = h2f(uu.x >> 16);
          const float e2 = h2f(uu.y);
          const float e3 = h2f(uu.y >> 16);
          step22(a0,a1,a2,a3,a4,a5,a6,a7,a8, pc, e0,e1,e2,e3, ebv,
                 f0,f1,f2,f3);
        }
        if (k == 13) measure();
        if (k == 15) apply();
      }
    }
    t0 += 16;
    pf += (size_t)16 * RW;
  }

  // ---- epilogue: -ln( (a[end] + a[end-1]) * 2^iacc ) ----
  const int end  = 2 * label_lens[b];
  const int base = 8 * lane;
  float sel = 0.f;
  if (base     == end || base     == end - 1) sel += a0;
  if (base + 1 == end || base + 1 == end - 1) sel += a1;
  if (base + 2 == end || base + 2 == end - 1) sel += a2;
  if (base + 3 == end || base + 3 == end - 1) sel += a3;
  if (base + 4 == end || base + 4 == end - 1) sel += a4;
  if (base + 5 == end || base + 5 == end - 1) sel += a5;
  if (base + 6 == end || base + 6 == end - 1) sel += a6;
  if (base + 7 == end || base + 7 == end - 1) sel += a7;
  if (lane == 63 && (end == 512 || end - 1 == 512)) sel += a8;
  sel = wave_sum_nn(sel);
  if (lane == 0) {
    const float cost = -((log2f(sel) + (float)iacc) * LN2);
    atomicAdd(out, cost);
  }
}

extern "C" void kernel_launch(void* const* d_in, const int* in_sizes, int n_in,
                              void* d_out, int out_size, void* d_ws, size_t ws_size,
                              hipStream_t stream) {
  const float* acts       = (const float*)d_in[0];
  const int*   labels     = (const int*)d_in[1];
  const int*   act_lens   = (const int*)d_in[2];
  const int*   label_lens = (const int*)d_in[3];
  float* out = (float*)d_out;
  ushort* P   = (ushort*)d_ws;                       // B*TP*512B = 34.6 MB
  float*  Pbk = (float*)(P + (size_t)B * TP * RW);   // B*TP*4B   = 0.27 MB

  (void)hipMemsetAsync(out, 0, sizeof(float) * out_size, stream);
  ctc_probs_kernel<<<dim3(TP / 32, B), 256, 0, stream>>>(acts, labels, P, Pbk);
  ctc_dp_kernel<<<B, 64, 0, stream>>>(P, Pbk, labels, act_lens, label_lens, out);
}

// Round 14
// 156.669 us; speedup vs baseline: 1.0465x; 1.0465x over previous
//
#include <hip/hip_runtime.h>
#include <hip/hip_fp16.h>
#include <math.h>

// CTC forward loss (warp-ctc semantics). T=1024, B=64, V=128, L=256, S=513.
//
// Round 15: R12 cooperative structure (measured best: dp 60.5us) + freight
// elimination. Per R12 counters, each wave issues ~20 instr/step but only
// ~10 are the DP recurrence; blanks (wave-uniform!) were going through the
// vector pipe with register ping-pong. Now: blanks via TWO s_load_dwordx8
// per 16-step block into SGPR octets (scalar pipe, K$), consumed directly
// as the SGPR operand of v_mul. Deletes per-step blank VMEM + all copies.
// Everything else identical to R12 (8 waves/block, core+overlap split,
// one barrier per 16 steps, block-shared pow-2 renorm).

#define L2E 1.4426950408889634f
#define LN2 0.6931471805599453f

constexpr int T   = 1024;
constexpr int B   = 64;
constexpr int V   = 128;
constexpr int L   = 256;
constexpr int RW  = 256;        // ushorts per P row: 256 label probs = 512 B
constexpr int TP  = T + 32;     // padded time rows per batch

typedef float v2f __attribute__((ext_vector_type(2)));
typedef float v8f __attribute__((ext_vector_type(8)));

// ---- DPP helpers (gfx9 ctrl codes: 0x111+ row_shr, 0x138 wave_shr:1,
//      0x142 row_bcast15, 0x143 row_bcast31) ----
template <int CTRL>
__device__ __forceinline__ float fdpp0(float x) {        // invalid lanes -> 0
  return __int_as_float(__builtin_amdgcn_update_dpp(
      0, __float_as_int(x), CTRL, 0xf, 0xf, true));
}
template <int CTRL>
__device__ __forceinline__ float fdppk(float x) {        // invalid lanes -> keep
  return __int_as_float(__builtin_amdgcn_update_dpp(
      __float_as_int(x), __float_as_int(x), CTRL, 0xf, 0xf, false));
}

__device__ __forceinline__ float wave_bcast63(float x) {
  return __int_as_float(__builtin_amdgcn_readlane(__float_as_int(x), 63));
}

__device__ __forceinline__ float wave_max(float x) {     // any sign
  x = fmaxf(x, fdppk<0x111>(x));
  x = fmaxf(x, fdppk<0x112>(x));
  x = fmaxf(x, fdppk<0x114>(x));
  x = fmaxf(x, fdppk<0x118>(x));
  x = fmaxf(x, fdppk<0x142>(x));
  x = fmaxf(x, fdppk<0x143>(x));
  return wave_bcast63(x);
}
__device__ __forceinline__ float wave_sum_nn(float x) {  // x >= 0
  x += fdpp0<0x111>(x);
  x += fdpp0<0x112>(x);
  x += fdpp0<0x114>(x);
  x += fdpp0<0x118>(x);
  x += fdpp0<0x142>(x);
  x += fdpp0<0x143>(x);
  return wave_bcast63(x);
}

__device__ __forceinline__ float h2f(uint bits) {
  return __half2float(__ushort_as_half((ushort)bits));
}

// ---------------- prologue: emission probabilities ----------------
// One block per (b, 32-row chunk); 4 waves x 8 rows. Labels loaded once per
// wave. Output PLAIN-ORDER: P row ushort j = prob(lab[j]); blank stored as
// ONE fp32 per (b, t) in Pbk. Block x==32 (rows 1024..1055) is zero pad.
__global__ __launch_bounds__(256) void ctc_probs_kernel(
    const float* __restrict__ acts,        // (T, B, V)
    const int* __restrict__ labels,        // (B, L)
    ushort* __restrict__ P,                // (B, TP, RW) fp16 bits, 512B rows
    float* __restrict__ Pbk) {             // (B, TP) scalar blank probs
  const int w    = threadIdx.x >> 6;
  const int lane = threadIdx.x & 63;
  const int b    = blockIdx.y;
  const int tb   = blockIdx.x * 32 + w * 8;   // first of this wave's 8 rows

  if (tb >= T) {                            // pad rows: zeros
    #pragma unroll
    for (int r = 0; r < 8; ++r) {
      uint2 z; z.x = 0u; z.y = 0u;
      *(uint2*)(P + ((size_t)b * TP + tb + r) * RW + 4 * lane) = z;
    }
    if (lane < 8) Pbk[(size_t)b * TP + tb + lane] = 0.f;
    return;
  }

  // labels once per wave; bpermute addresses/shifts precomputed
  const int4 lvv = *(const int4*)(labels + (size_t)b * L + 4 * lane);
  const int ba0 = (lvv.x & ~1) * 2, sh0 = (lvv.x & 1) << 4;
  const int ba1 = (lvv.y & ~1) * 2, sh1 = (lvv.y & 1) << 4;
  const int ba2 = (lvv.z & ~1) * 2, sh2 = (lvv.z & 1) << 4;
  const int ba3 = (lvv.w & ~1) * 2, sh3 = (lvv.w & 1) << 4;

  #pragma unroll
  for (int r = 0; r < 8; ++r) {
    const int t = tb + r;
    const float* row = acts + ((size_t)t * B + b) * V;
    const float2 v2 = *(const float2*)(row + 2 * lane);
    const float e0 = exp2f(fmaf(v2.x, L2E, -32.0f));
    const float e1 = exp2f(fmaf(v2.y, L2E, -32.0f));
    const float sm = wave_sum_nn(e0 + e1);
    const float rc = __builtin_amdgcn_rcpf(sm);
    const auto pk = __builtin_amdgcn_cvt_pkrtz(e0 * rc, e1 * rc);
    uint hp;                                // [p_{2l} | p_{2l+1} << 16]
    __builtin_memcpy(&hp, &pk, 4);
    const uint g0 = (uint)__builtin_amdgcn_ds_bpermute(ba0, (int)hp);
    const uint g1 = (uint)__builtin_amdgcn_ds_bpermute(ba1, (int)hp);
    const uint g2 = (uint)__builtin_amdgcn_ds_bpermute(ba2, (int)hp);
    const uint g3 = (uint)__builtin_amdgcn_ds_bpermute(ba3, (int)hp);
    const uint h0 = (g0 >> sh0) & 0xffffu;
    const uint h1 = (g1 >> sh1) & 0xffffu;
    const uint h2 = (g2 >> sh2) & 0xffffu;
    const uint h3 = (g3 >> sh3);
    uint2 o;
    o.x = h0 | (h1 << 16);                  // PLAIN order: labels 4l,4l+1
    o.y = h2 | (h3 << 16);                  //              labels 4l+2,4l+3
    *(uint2*)(P + ((size_t)b * TP + t) * RW + 4 * lane) = o;
    if (lane == 0)
      Pbk[(size_t)b * TP + t] = e0 * rc;    // vocab 0 = lane0's p0
  }
}

// ---------------- DP kernel: 8 cooperating waves per batch ----------------
// Wave w, lane l holds pair index k = 32w-32+l -> cells (2k, 2k+1):
// even cell = blank-emission, odd cell = label k. Core = lanes 32..63
// (cells [64w, 64w+64)); lanes 0..31 = left overlap (refreshed every 16
// steps from wave w-1's core). Wave 7 lane 63 also owns cell 512 in a8.
__global__ __launch_bounds__(512) void ctc_dp_kernel(
    const ushort* __restrict__ P,
    const float* __restrict__ Pbk,
    const int* __restrict__ labels,
    const int* __restrict__ act_lens,
    const int* __restrict__ label_lens,
    float* __restrict__ out) {
  __shared__ float shc[2][9 * 64];   // [buf][slot*64+j]; slot w+1 = wave w core
  __shared__ float shm[2][8];        // per-wave maxes
  __shared__ float shs[8];           // epilogue partials
  const int b    = blockIdx.x;
  const int w    = threadIdx.x >> 6;
  const int lane = threadIdx.x & 63;
  const int k    = 32 * w - 32 + lane;     // global pair index (<0 on wave 0)
  const int kc   = (k < 0) ? 0 : k;
  const ushort* __restrict__ Pb = P + (size_t)b * TP * RW;
  const float*  __restrict__ Bk = Pbk + (size_t)b * TP;

  if (threadIdx.x < 64) {                  // slot 0 = zeros (wave 0's source)
    shc[0][threadIdx.x] = 0.f;
    shc[1][threadIdx.x] = 0.f;
  }

  // skip flag for odd cell 2k+1 (label k): needs lab[k] != lab[k-1], k>=1
  float f = 0.f;
  if (k >= 1) {
    const int la  = labels[(size_t)b * L + k];
    const int lam = labels[(size_t)b * L + k - 1];
    f = (la != 0 && la != lam) ? 1.f : 0.f;
  }

  const int AL = act_lens[b];
  const ushort* __restrict__ PbL = Pb + kc;  // lane's label-prob column

  // ---- t=0 init: cell0 = blank(0), cell1 = p(lab0, 0); rest 0 ----
  v2f Pp; Pp.x = 0.f; Pp.y = 0.f;
  float a8 = 0.f;
  {
    const float eb0 = Bk[0];
    const float e00 = h2f(PbL[0]);
    if (k == 0) { Pp.x = eb0; Pp.y = e00; }  // both waves holding k==0
  }
  int iacc = 0;

  // ---- prefetch: emissions 16 rows deep (VGPR) ----
  uint ev[16];
  #pragma unroll
  for (int j = 0; j < 16; ++j) ev[j] = PbL[(size_t)(1 + j) * RW];

  const ushort* pf = PbL + (size_t)17 * RW;
  int t0 = 1;
  #pragma unroll 1
  for (int blk = 0; blk < 64; ++blk) {      // 64 x 16 = steps t=1..1024
    const int bb = blk & 1;
    // blanks for steps t0..t0+15 via the SCALAR pipe: 2x s_load_dwordx8
    // into SGPR octets; rows <= 1024 < TP. Dataflow-tied wait (rule #18).
    v8f sA, sB;
    {
      const float* bp = Bk + t0;            // wave-uniform address
      asm volatile("s_load_dwordx8 %0, %1, 0x0"  : "=s"(sA) : "s"(bp));
      asm volatile("s_load_dwordx8 %0, %1, 0x20" : "=s"(sB) : "s"(bp));
      asm volatile("s_waitcnt lgkmcnt(0)" : "+s"(sA), "+s"(sB));
    }
    const ushort* pfA = pf;                 // dual bases: offsets fit 13-bit
    const ushort* pfB = pf + (size_t)8 * RW;
    const bool fast = (t0 + 16 <= AL);
    if (fast) {
      #pragma unroll
      for (int kk = 0; kk < 16; ++kk) {
        const uint uu = ev[kk];
        ev[kk] = ((kk < 8) ? pfA : pfB)[(size_t)(kk & 7) * RW];
        const float ebv = (kk < 8) ? sA[kk] : sB[kk - 8];  // SGPR operand
        const float pc = fdpp0<0x138>(Pp.y);   // prev lane's odd cell
        const float e  = h2f(uu);
        const float sx = Pp.x + pc;
        const float ty = fmaf(f, pc, Pp.y + Pp.x);
        const float s8 = a8 + Pp.y;
        Pp.x = sx * ebv;
        Pp.y = ty * e;
        a8 = s8 * ebv;
        if (kk == 13) {                     // measure early: hide wave_max
          const float m = fmaxf(fmaxf(Pp.x, Pp.y), a8);
          const float pm = wave_max(m);
          if (lane == 0) shm[bb][w] = pm;
        }
      }
    } else {
      #pragma unroll
      for (int kk = 0; kk < 16; ++kk) {
        const uint uu = ev[kk];
        ev[kk] = ((kk < 8) ? pfA : pfB)[(size_t)(kk & 7) * RW];
        const float ebv = (kk < 8) ? sA[kk] : sB[kk - 8];
        if ((t0 + kk) < AL) {               // AL block-uniform
          const float pc = fdpp0<0x138>(Pp.y);
          const float e  = h2f(uu);
          const float sx = Pp.x + pc;
          const float ty = fmaf(f, pc, Pp.y + Pp.x);
          const float s8 = a8 + Pp.y;
          Pp.x = sx * ebv;
          Pp.y = ty * e;
          a8 = s8 * ebv;
        }
        if (kk == 13) {
          const float m = fmaxf(fmaxf(Pp.x, Pp.y), a8);
          const float pm = wave_max(m);
          if (lane == 0) shm[bb][w] = pm;
        }
      }
    }
    // ---- boundary: core export, ONE barrier, refresh + shared scale ----
    if (lane >= 32)
      *(v2f*)&shc[bb][(w + 1) * 64 + 2 * (lane - 32)] = Pp;
    __syncthreads();
    const float* mm = shm[bb];
    const float bm = fmaxf(fmaxf(fmaxf(mm[0], mm[1]), fmaxf(mm[2], mm[3])),
                           fmaxf(fmaxf(mm[4], mm[5]), fmaxf(mm[6], mm[7])));
    if (lane < 32)
      Pp = *(const v2f*)&shc[bb][w * 64 + 2 * lane];
    {
      // pow-2 scale 2^(175-e), +48 headroom (validated R10..R12, absmax 0)
      const uint mb2 = __float_as_uint(bm);
      int e = (int)((mb2 >> 23) & 0xffu); if (e < 48) e = 48;
      const float r = __uint_as_float((uint)(302 - e) << 23);
      iacc += (e - 175);
      Pp.x *= r; Pp.y *= r; a8 *= r;
    }
    t0 += 16;
    pf += (size_t)16 * RW;
  }

  // ---- epilogue: -ln( (a[end] + a[end-1]) * 2^iacc ) ----
  // contributions from CORE cells only (no double count with overlaps)
  const int end = 2 * label_lens[b];
  float sel = 0.f;
  if (lane >= 32) {
    const int c0 = 64 * w + 2 * (lane - 32);
    if (c0 == end || c0 == end - 1) sel += Pp.x;
    if (c0 + 1 == end || c0 + 1 == end - 1) sel += Pp.y;
  }
  if (w == 7 && lane == 63 && end == 512) sel += a8;
  sel = wave_sum_nn(sel);
  if (lane == 0) shs[w] = sel;
  __syncthreads();
  if (threadIdx.x == 0) {
    float s = 0.f;
    #pragma unroll
    for (int j = 0; j < 8; ++j) s += shs[j];
    const float cost = -((log2f(s) + (float)iacc) * LN2);
    atomicAdd(out, cost);
  }
}

extern "C" void kernel_launch(void* const* d_in, const int* in_sizes, int n_in,
                              void* d_out, int out_size, void* d_ws, size_t ws_size,
                              hipStream_t stream) {
  const float* acts       = (const float*)d_in[0];
  const int*   labels     = (const int*)d_in[1];
  const int*   act_lens   = (const int*)d_in[2];
  const int*   label_lens = (const int*)d_in[3];
  float* out = (float*)d_out;
  ushort* P   = (ushort*)d_ws;                       // B*TP*512B = 34.6 MB
  float*  Pbk = (float*)(P + (size_t)B * TP * RW);   // B*TP*4B   = 0.27 MB

  (void)hipMemsetAsync(out, 0, sizeof(float) * out_size, stream);
  ctc_probs_kernel<<<dim3(TP / 32, B), 256, 0, stream>>>(acts, labels, P, Pbk);
  ctc_dp_kernel<<<B, 512, 0, stream>>>(P, Pbk, labels, act_lens, label_lens, out);
}